// Round 8
// baseline (374.269 us; speedup 1.0000x reference)
//
#include <hip/hip_runtime.h>
#include <hip/hip_bf16.h>
#include <stdint.h>

#define NROWS 8192
#define DDIM  256
#define SIGMA_INV 10.0f

#define BM 64
#define BN 64
#define NSPLIT 4                  // chunk=b&3; XCD=b%8 -> one 2MB j-slice per XCD
                                  // (L2-resident, round-2 lesson).
#define JCHUNK (NROWS / NSPLIT)   // 2048
#define NITER  (JCHUNK / BN)      // 32
#define PSTR   72                 // pl row stride in halfs (144B, 16B-aligned)

typedef __attribute__((ext_vector_type(8))) short bf16x8;
typedef __attribute__((ext_vector_type(4))) float f32x4;

__device__ inline unsigned short f2bf(float x) {
  __hip_bfloat16 h = __float2bfloat16(x);
  return *reinterpret_cast<unsigned short*>(&h);
}

// ---------------- K0: L2-normalize rows -> bf16 ----------------
__global__ __launch_bounds__(256) void normalize_k(const float* __restrict__ emb,
                                                   unsigned short* __restrict__ embn) {
  const int w = threadIdx.x >> 6, lane = threadIdx.x & 63;
  const int row = blockIdx.x * 4 + w;
  const float4* src = (const float4*)(emb + (size_t)row * DDIM);
  float4 v = src[lane];
  float ss = v.x * v.x + v.y * v.y + v.z * v.z + v.w * v.w;
  for (int off = 32; off >= 1; off >>= 1) ss += __shfl_xor(ss, off);
  const float sc = 1.0f / fmaxf(sqrtf(ss), 1e-12f);
  ushort4 o;
  o.x = f2bf(v.x * sc); o.y = f2bf(v.y * sc);
  o.z = f2bf(v.z * sc); o.w = f2bf(v.w * sc);
  ((ushort4*)(embn + (size_t)row * DDIM))[lane] = o;
}

// ---------------- K0b: emb[N][D] fp32 -> vt TILED bf16 ----------------
// vt layout: [jtile = j/64][d = 0..255][jj = j%64]  (32KB contiguous per j-tile)
__global__ __launch_bounds__(256) void transpose_k(const float* __restrict__ emb,
                                                   unsigned short* __restrict__ vt) {
  __shared__ float tile[64][65];
  const int r0 = blockIdx.x * 64, c0 = blockIdx.y * 64;
  const int tr = threadIdx.x >> 6, tc = threadIdx.x & 63;
  for (int i = 0; i < 16; ++i)
    tile[i * 4 + tr][tc] = emb[(size_t)(r0 + i * 4 + tr) * DDIM + c0 + tc];
  __syncthreads();
  unsigned short* dst = vt + (size_t)(r0 >> 6) * (DDIM * 64);   // jtile = r0/64
  for (int i = 0; i < 16; ++i)
    dst[(size_t)(c0 + i * 4 + tr) * 64 + tc] = f2bf(tile[tc][i * 4 + tr]);
}

// ---------------- F: fused  S=Qn.Knt -> exp -> O += P.V, row sums ----------------
// ROUND-8 RESTRUCTURE: dissolve the phase convoy.
// Evidence (R0-R7): T_block-iter ~2.4-2.7us invariant to occupancy (2 or 4
// blocks/CU, R7), BM, DMA cover (R3), skew (R6); all pipes <25%. Diagnosis:
// the 2-barrier loop [B1 vmcnt0-drain -> G1(LDS) -> exp(VALU) -> B2 -> G2(VMEM)]
// serializes single-pipe phases and barriers convoy all waves into the SAME
// phase -> extra waves queue on the same pipe (R7's null result). m233 measured
// this structure class at ~72% overhead on GEMM.
// Fix, in one move:
//  * NO kn LDS, NO global_load_lds: K B-frags load DIRECT from embn (identical
//    instruction count, 16B/thread; data is L2-resident). Kills B1's vmcnt(0)
//    drain and 33KB LDS.
//  * pl double-buffered (2 x 9KB): G2 runs ONE TILE BEHIND (reads pl_prev)
//    while G1(it)+exp(it) produce pl_cur -> ONE barrier per iter, no vmem
//    drain anywhere, and the single scheduler region contains TWO independent
//    MFMA chains (sacc, oacc) + global loads + LDS ops + exp VALU to overlap.
// grid = 128 mblk x 4 chunks = 512 blocks = 2/CU (reg-binned; occupancy proven
// not the lever in R7 -- structure is).
__global__ __launch_bounds__(256) void fused_k(
    const unsigned short* __restrict__ embn,  // [N][D] bf16 normalized
    const unsigned short* __restrict__ vt,    // tiled [N/64][256][64] bf16
    float* __restrict__ out,                  // [N][D] fp32, pre-zeroed, atomic accum
    float* __restrict__ l_part)               // [N] fp32, pre-zeroed, atomic accum
{
  __shared__ unsigned short pl[2][BM * PSTR]; // 2 x 9 KB, double-buffered P transit

  const int tid = threadIdx.x;
  const int w = tid >> 6, lane = tid & 63;
  const int mg = w >> 1, dh = w & 1;          // m-group, d-half
  const int q = lane >> 4, c = lane & 15;
  const int chunk = blockIdx.x & 3;
  const int mblk = blockIdx.x >> 2;
  const int row0 = mblk * BM + mg * 32;
  const int t0 = chunk * NITER;               // j-tile range [t0, t1)
  const int t1 = t0 + NITER;

  // Q fragments resident: A[m=lane&15][k=q*8+j]
  bf16x8 qa[2][8];
  for (int mt = 0; mt < 2; ++mt)
    for (int k = 0; k < 8; ++k)
      qa[mt][k] = *(const bf16x8*)(embn + (size_t)(row0 + mt * 16 + c) * DDIM + k * 32 + q * 8);

  f32x4 oacc[2][8];
  for (int mt = 0; mt < 2; ++mt)
    for (int u = 0; u < 8; ++u) oacc[mt][u] = {0.f, 0.f, 0.f, 0.f};
  float lacc[2][4] = {};

  for (int it = t0; it < t1; ++it) {
    // ---- single barrier per iter ----
    // guarantees: all waves' pl_cur(it-1) writes retired (lgkmcnt0 below),
    // all waves' pl_prev reads (G2(it-2)) retired. No vmem involvement.
    __builtin_amdgcn_sched_barrier(0);
    asm volatile("s_waitcnt lgkmcnt(0)" ::: "memory");
    __builtin_amdgcn_sched_barrier(0);
    __builtin_amdgcn_s_barrier();
    __builtin_amdgcn_sched_barrier(0);

    // V fragments for G2(it-1): issued first so their latency hides under G1
    bf16x8 vfrag[2][8];
    if (it > t0) {
      const unsigned short* vtile = vt + (size_t)(it - 1) * (DDIM * BN);
      for (int kk = 0; kk < 2; ++kk)
        for (int u = 0; u < 8; ++u)
          vfrag[kk][u] = *(const bf16x8*)(vtile + (size_t)(dh * 128 + u * 16 + c) * BN + kk * 32 + q * 8);
    }

    // ---- G1(it): S[32x64] = Q . K^T, B-frags DIRECT from embn (L2) ----
    // B[n=c][k]: row (it*BN + dh*32 + nt*16 + c), 16B at col k*32+q*8
    f32x4 sacc[2][2];
    for (int mt = 0; mt < 2; ++mt)
      for (int nt = 0; nt < 2; ++nt) sacc[mt][nt] = {0.f, 0.f, 0.f, 0.f};
    {
      const unsigned short* brow0 = embn + (size_t)(it * BN + dh * 32 + c) * DDIM;
      const unsigned short* brow1 = brow0 + (size_t)16 * DDIM;
      for (int k = 0; k < 8; ++k) {
        bf16x8 b0 = *(const bf16x8*)(brow0 + k * 32 + q * 8);
        bf16x8 b1 = *(const bf16x8*)(brow1 + k * 32 + q * 8);
        for (int mt = 0; mt < 2; ++mt) {
          sacc[mt][0] = __builtin_amdgcn_mfma_f32_16x16x32_bf16(qa[mt][k], b0, sacc[mt][0], 0, 0, 0);
          sacc[mt][1] = __builtin_amdgcn_mfma_f32_16x16x32_bf16(qa[mt][k], b1, sacc[mt][1], 0, 0, 0);
        }
      }
    }

    // ---- G2(it-1): O += P_prev . V, independent MFMA chain, overlaps G1 ----
    if (it > t0) {
      const unsigned short* plp = pl[(it + 1) & 1];   // == (it-1)&1
      for (int kk = 0; kk < 2; ++kk) {
        bf16x8 ap0 = *(const bf16x8*)(plp + (mg * 32 + c) * PSTR + kk * 32 + q * 8);
        bf16x8 ap1 = *(const bf16x8*)(plp + (mg * 32 + 16 + c) * PSTR + kk * 32 + q * 8);
        for (int u = 0; u < 8; ++u) {
          oacc[0][u] = __builtin_amdgcn_mfma_f32_16x16x32_bf16(ap0, vfrag[kk][u], oacc[0][u], 0, 0, 0);
          oacc[1][u] = __builtin_amdgcn_mfma_f32_16x16x32_bf16(ap1, vfrag[kk][u], oacc[1][u], 0, 0, 0);
        }
      }
    }

    // ---- exp(it) -> pl_cur (fixed shift 10; logits<=10, shift-invariant) ----
    {
      unsigned short* plc = pl[it & 1];
      for (int mt = 0; mt < 2; ++mt)
        for (int nt = 0; nt < 2; ++nt)
          for (int r = 0; r < 4; ++r) {
            const float p = __expf(fmaf(SIGMA_INV, sacc[mt][nt][r], -SIGMA_INV));
            lacc[mt][r] += p;
            // C/D layout: row = q*4+r, col = c
            plc[(mg * 32 + mt * 16 + q * 4 + r) * PSTR + dh * 32 + nt * 16 + c] = f2bf(p);
          }
    }
  }

  // ---- tail: G2 for the last tile (t1-1) ----
  {
    __builtin_amdgcn_sched_barrier(0);
    asm volatile("s_waitcnt lgkmcnt(0)" ::: "memory");
    __builtin_amdgcn_sched_barrier(0);
    __builtin_amdgcn_s_barrier();
    __builtin_amdgcn_sched_barrier(0);

    const unsigned short* vtile = vt + (size_t)(t1 - 1) * (DDIM * BN);
    const unsigned short* plp = pl[(t1 - 1) & 1];
    for (int kk = 0; kk < 2; ++kk) {
      bf16x8 ap0 = *(const bf16x8*)(plp + (mg * 32 + c) * PSTR + kk * 32 + q * 8);
      bf16x8 ap1 = *(const bf16x8*)(plp + (mg * 32 + 16 + c) * PSTR + kk * 32 + q * 8);
      for (int u = 0; u < 8; ++u) {
        bf16x8 vf = *(const bf16x8*)(vtile + (size_t)(dh * 128 + u * 16 + c) * BN + kk * 32 + q * 8);
        oacc[0][u] = __builtin_amdgcn_mfma_f32_16x16x32_bf16(ap0, vf, oacc[0][u], 0, 0, 0);
        oacc[1][u] = __builtin_amdgcn_mfma_f32_16x16x32_bf16(ap1, vf, oacc[1][u], 0, 0, 0);
      }
    }
  }

  // epilogue: row sums across the 16 c-lanes, then device atomics
  for (int mt = 0; mt < 2; ++mt)
    for (int r = 0; r < 4; ++r) {
      float s = lacc[mt][r];
      s += __shfl_xor(s, 1); s += __shfl_xor(s, 2);
      s += __shfl_xor(s, 4); s += __shfl_xor(s, 8);
      if (c == 0)
        atomicAdd(&l_part[row0 + mt * 16 + q * 4 + r], s);
    }
  for (int mt = 0; mt < 2; ++mt)
    for (int u = 0; u < 8; ++u)
      for (int r = 0; r < 4; ++r)
        atomicAdd(&out[(size_t)(row0 + mt * 16 + q * 4 + r) * DDIM + dh * 128 + u * 16 + c],
                  oacc[mt][u][r]);
}

// ---------------- K4: divide by row sums ----------------
__global__ __launch_bounds__(256) void finalize_k(float* __restrict__ out,
                                                  const float* __restrict__ l_part) {
  const int row = blockIdx.x, t = threadIdx.x;
  out[(size_t)row * DDIM + t] /= l_part[row];
}

extern "C" void kernel_launch(void* const* d_in, const int* in_sizes, int n_in,
                              void* d_out, int out_size, void* d_ws, size_t ws_size,
                              hipStream_t stream) {
  const float* emb = (const float*)d_in[0];
  float* out = (float*)d_out;
  char* ws = (char*)d_ws;
  // ws layout: embn 4MB | vt 4MB | l_part 32KB
  unsigned short* embn = (unsigned short*)ws;
  unsigned short* vt   = (unsigned short*)(ws + ((size_t)4 << 20));
  float* l_part        = (float*)(ws + ((size_t)8 << 20));

  hipMemsetAsync(out, 0, (size_t)NROWS * DDIM * sizeof(float), stream);
  hipMemsetAsync(l_part, 0, (size_t)NROWS * sizeof(float), stream);

  normalize_k<<<NROWS / 4, 256, 0, stream>>>(emb, embn);
  transpose_k<<<dim3(NROWS / 64, DDIM / 64), 256, 0, stream>>>(emb, vt);
  fused_k<<<(NROWS / BM) * NSPLIT, 256, 0, stream>>>(embn, vt, out, l_part);
  finalize_k<<<NROWS, 256, 0, stream>>>(out, l_part);
}